// Round 9
// baseline (248.003 us; speedup 1.0000x reference)
//
#include <hip/hip_runtime.h>

#define NUM_USERS 100000
#define NUM_ITEMS 100000
#define EMB_DIM   128
#define NUM_EDGES 600000
#define NN        200000   // N_NODES

#define SCAN_B  256
#define SCAN_NB ((NN + SCAN_B - 1) / SCAN_B)   // 782
#define CNT_NB  ((NUM_EDGES + 255) / 256)

typedef __attribute__((ext_vector_type(8))) unsigned short ushort8_t;
typedef __attribute__((ext_vector_type(4))) float float4_t;

// bf16 helpers (RNE rounding)
__device__ inline float bf2f(unsigned short u) {
    unsigned int x = ((unsigned int)u) << 16;
    return __builtin_bit_cast(float, x);
}
__device__ inline unsigned short f2bf(float f) {
    unsigned int x = __builtin_bit_cast(unsigned int, f);
    x += 0x7fffu + ((x >> 16) & 1u);   // round-to-nearest-even
    return (unsigned short)(x >> 16);
}

// ---------- emb f32 -> x0 bf16 (streaming, 32B/thread) ----------
// NT loads: emb is single-use here; keep L3 for x0/x1/x2.
__global__ void k_conv(const float* __restrict__ emb, ushort* __restrict__ x0) {
    int i = blockIdx.x * blockDim.x + threadIdx.x;   // over NN*EMB_DIM/8
    const float4_t v0 =
        __builtin_nontemporal_load(reinterpret_cast<const float4_t*>(emb) + 2 * i);
    const float4_t v1 =
        __builtin_nontemporal_load(reinterpret_cast<const float4_t*>(emb) + 2 * i + 1);
    ushort8_t w;
#pragma unroll
    for (int j = 0; j < 4; ++j) { w[j] = f2bf(v0[j]); w[j + 4] = f2bf(v1[j]); }
    *reinterpret_cast<ushort8_t*>(x0 + (size_t)i * 8) = w;
}

// ---------- degree count (in-degree over col) ----------
__global__ void k_count(const int* __restrict__ col, int* __restrict__ deg) {
    int e = blockIdx.x * blockDim.x + threadIdx.x;
    if (e < NUM_EDGES) atomicAdd(&deg[col[e]], 1);
}

// ---------- scan part 1 + deg_inv_sqrt fused ----------
__global__ void k_scan1(const int* __restrict__ deg, int* __restrict__ rp,
                        int* __restrict__ bsum, float* __restrict__ dis) {
    __shared__ int s[SCAN_B];
    int tid = threadIdx.x;
    int i = blockIdx.x * SCAN_B + tid;
    int v = (i < NN) ? deg[i] : 0;
    s[tid] = v;
    __syncthreads();
    for (int off = 1; off < SCAN_B; off <<= 1) {
        int t = (tid >= off) ? s[tid - off] : 0;
        __syncthreads();
        s[tid] += t;
        __syncthreads();
    }
    if (i < NN) {
        rp[i]  = s[tid] - v;                    // exclusive within block
        dis[i] = (v > 0) ? 1.0f / sqrtf((float)v) : 0.0f;
    }
    if (tid == SCAN_B - 1) bsum[blockIdx.x] = s[tid];
}

__global__ void k_scan2(int* __restrict__ bsum) {
    __shared__ int s[1024];
    int tid = threadIdx.x;
    int v = (tid < SCAN_NB) ? bsum[tid] : 0;
    s[tid] = v;
    __syncthreads();
    for (int off = 1; off < 1024; off <<= 1) {
        int t = (tid >= off) ? s[tid - off] : 0;
        __syncthreads();
        s[tid] += t;
        __syncthreads();
    }
    if (tid < SCAN_NB) bsum[tid] = s[tid] - v;
}

__global__ void k_scan3(int* __restrict__ rp, const int* __restrict__ bsum) {
    int i = blockIdx.x * SCAN_B + threadIdx.x;
    if (i < NN) rp[i] += bsum[blockIdx.x];
    if (i == 0) rp[NN] = NUM_EDGES;
}

// ---------- CSR fill, packed (src, coef) ----------
__global__ void k_fill(const int* __restrict__ row, const int* __restrict__ col,
                       const float* __restrict__ dis, const int* __restrict__ rp,
                       int* __restrict__ cursor, int2* __restrict__ csr) {
    int e = blockIdx.x * blockDim.x + threadIdx.x;
    if (e >= NUM_EDGES) return;
    int r = row[e], c = col[e];
    int p = rp[c] + atomicAdd(&cursor[c], 1);
    csr[p] = make_int2(r, __builtin_bit_cast(int, dis[r] * dis[c]));
}

// ---------- propagation layer: y = A * x (bf16), store bf16 ----------
// 8 lanes/node, 32B/lane (2x ushort8); 4-wide edge unroll -> 8 independent
// 16B gathers in flight per thread. Plain stores: x1/x2 are re-read next.
__global__ void k_gath(const ushort* __restrict__ x, const int* __restrict__ rp,
                       const int2* __restrict__ csr, ushort* __restrict__ xn) {
    int t    = blockIdx.x * blockDim.x + threadIdx.x;
    int node = t >> 3;
    int lane = t & 7;
    if (node >= NN) return;
    int beg = rp[node], end = rp[node + 1];
    float a[16] = {0};
    const int bd = lane * 16;
    for (int k = beg; k < end; k += 4) {
        const int last = end - 1;
        const int k1 = min(k + 1, last), k2 = min(k + 2, last), k3 = min(k + 3, last);
        const int2 e0 = csr[k], e1 = csr[k1], e2 = csr[k2], e3 = csr[k3];
        const float c0 = __builtin_bit_cast(float, e0.y);
        const float c1 = (k + 1 <= last) ? __builtin_bit_cast(float, e1.y) : 0.0f;
        const float c2 = (k + 2 <= last) ? __builtin_bit_cast(float, e2.y) : 0.0f;
        const float c3 = (k + 3 <= last) ? __builtin_bit_cast(float, e3.y) : 0.0f;
        const ushort* p0 = x + (size_t)e0.x * EMB_DIM + bd;
        const ushort* p1 = x + (size_t)e1.x * EMB_DIM + bd;
        const ushort* p2 = x + (size_t)e2.x * EMB_DIM + bd;
        const ushort* p3 = x + (size_t)e3.x * EMB_DIM + bd;
        const ushort8_t v0a = *reinterpret_cast<const ushort8_t*>(p0);
        const ushort8_t v1a = *reinterpret_cast<const ushort8_t*>(p1);
        const ushort8_t v2a = *reinterpret_cast<const ushort8_t*>(p2);
        const ushort8_t v3a = *reinterpret_cast<const ushort8_t*>(p3);
        const ushort8_t v0b = *reinterpret_cast<const ushort8_t*>(p0 + 8);
        const ushort8_t v1b = *reinterpret_cast<const ushort8_t*>(p1 + 8);
        const ushort8_t v2b = *reinterpret_cast<const ushort8_t*>(p2 + 8);
        const ushort8_t v3b = *reinterpret_cast<const ushort8_t*>(p3 + 8);
#pragma unroll
        for (int j = 0; j < 8; ++j) {
            a[j]     += c0 * bf2f(v0a[j]) + c1 * bf2f(v1a[j]) +
                        c2 * bf2f(v2a[j]) + c3 * bf2f(v3a[j]);
            a[j + 8] += c0 * bf2f(v0b[j]) + c1 * bf2f(v1b[j]) +
                        c2 * bf2f(v2b[j]) + c3 * bf2f(v3b[j]);
        }
    }
    ushort8_t wa, wb;
#pragma unroll
    for (int j = 0; j < 8; ++j) { wa[j] = f2bf(a[j]); wb[j] = f2bf(a[j + 8]); }
    ushort* q = xn + (size_t)node * EMB_DIM + bd;
    *reinterpret_cast<ushort8_t*>(q)     = wa;
    *reinterpret_cast<ushort8_t*>(q + 8) = wb;
}

// ---------- final: y3 = A * x2;  out = (x0 + x1 + x2 + y3) * 0.25 ----------
// 8 lanes/node, 32B/lane — same ILP layout as k_gath; NT store for out only.
__global__ void k_final(const ushort* __restrict__ x2, const int* __restrict__ rp,
                        const int2* __restrict__ csr,
                        const ushort* __restrict__ x0, const ushort* __restrict__ x1,
                        float* __restrict__ out) {
    int t    = blockIdx.x * blockDim.x + threadIdx.x;
    int node = t >> 3;
    int lane = t & 7;
    if (node >= NN) return;
    int beg = rp[node], end = rp[node + 1];
    float a[16] = {0};
    const int bd = lane * 16;
    for (int k = beg; k < end; k += 4) {
        const int last = end - 1;
        const int k1 = min(k + 1, last), k2 = min(k + 2, last), k3 = min(k + 3, last);
        const int2 e0 = csr[k], e1 = csr[k1], e2 = csr[k2], e3 = csr[k3];
        const float c0 = __builtin_bit_cast(float, e0.y);
        const float c1 = (k + 1 <= last) ? __builtin_bit_cast(float, e1.y) : 0.0f;
        const float c2 = (k + 2 <= last) ? __builtin_bit_cast(float, e2.y) : 0.0f;
        const float c3 = (k + 3 <= last) ? __builtin_bit_cast(float, e3.y) : 0.0f;
        const ushort* p0 = x2 + (size_t)e0.x * EMB_DIM + bd;
        const ushort* p1 = x2 + (size_t)e1.x * EMB_DIM + bd;
        const ushort* p2 = x2 + (size_t)e2.x * EMB_DIM + bd;
        const ushort* p3 = x2 + (size_t)e3.x * EMB_DIM + bd;
        const ushort8_t v0a = *reinterpret_cast<const ushort8_t*>(p0);
        const ushort8_t v1a = *reinterpret_cast<const ushort8_t*>(p1);
        const ushort8_t v2a = *reinterpret_cast<const ushort8_t*>(p2);
        const ushort8_t v3a = *reinterpret_cast<const ushort8_t*>(p3);
        const ushort8_t v0b = *reinterpret_cast<const ushort8_t*>(p0 + 8);
        const ushort8_t v1b = *reinterpret_cast<const ushort8_t*>(p1 + 8);
        const ushort8_t v2b = *reinterpret_cast<const ushort8_t*>(p2 + 8);
        const ushort8_t v3b = *reinterpret_cast<const ushort8_t*>(p3 + 8);
#pragma unroll
        for (int j = 0; j < 8; ++j) {
            a[j]     += c0 * bf2f(v0a[j]) + c1 * bf2f(v1a[j]) +
                        c2 * bf2f(v2a[j]) + c3 * bf2f(v3a[j]);
            a[j + 8] += c0 * bf2f(v0b[j]) + c1 * bf2f(v1b[j]) +
                        c2 * bf2f(v2b[j]) + c3 * bf2f(v3b[j]);
        }
    }
    const size_t o = (size_t)node * EMB_DIM + bd;
    const ushort8_t w0a = *reinterpret_cast<const ushort8_t*>(x0 + o);
    const ushort8_t w0b = *reinterpret_cast<const ushort8_t*>(x0 + o + 8);
    const ushort8_t w1a = *reinterpret_cast<const ushort8_t*>(x1 + o);
    const ushort8_t w1b = *reinterpret_cast<const ushort8_t*>(x1 + o + 8);
    const ushort8_t w2a = *reinterpret_cast<const ushort8_t*>(x2 + o);
    const ushort8_t w2b = *reinterpret_cast<const ushort8_t*>(x2 + o + 8);
    float4_t r0, r1, r2, r3;
#pragma unroll
    for (int j = 0; j < 4; ++j) {
        r0[j] = (bf2f(w0a[j])     + bf2f(w1a[j])     + bf2f(w2a[j])     + a[j])      * 0.25f;
        r1[j] = (bf2f(w0a[j + 4]) + bf2f(w1a[j + 4]) + bf2f(w2a[j + 4]) + a[j + 4])  * 0.25f;
        r2[j] = (bf2f(w0b[j])     + bf2f(w1b[j])     + bf2f(w2b[j])     + a[j + 8])  * 0.25f;
        r3[j] = (bf2f(w0b[j + 4]) + bf2f(w1b[j + 4]) + bf2f(w2b[j + 4]) + a[j + 12]) * 0.25f;
    }
    // out is never re-read: nontemporal keeps x0/x1/x2 L3-resident for the gather
    float4_t* q = reinterpret_cast<float4_t*>(out + o);
    __builtin_nontemporal_store(r0, q);
    __builtin_nontemporal_store(r1, q + 1);
    __builtin_nontemporal_store(r2, q + 2);
    __builtin_nontemporal_store(r3, q + 3);
}

extern "C" void kernel_launch(void* const* d_in, const int* in_sizes, int n_in,
                              void* d_out, int out_size, void* d_ws, size_t ws_size,
                              hipStream_t stream) {
    const int*   edges = (const int*)d_in[0];
    const int*   row   = edges;               // edge_index[0]
    const int*   col   = edges + NUM_EDGES;   // edge_index[1]
    const float* emb   = (const float*)d_in[1];
    float*       out   = (float*)d_out;

    char*  ws  = (char*)d_ws;
    size_t off = 0;
    auto alloc = [&](size_t bytes) {
        void* p = ws + off;
        off += (bytes + 255) & ~(size_t)255;
        return p;
    };
    ushort* x0     = (ushort*)alloc(sizeof(ushort) * (size_t)NN * EMB_DIM); // 51.2 MB
    ushort* x1     = (ushort*)alloc(sizeof(ushort) * (size_t)NN * EMB_DIM); // 51.2 MB
    ushort* x2     = (ushort*)alloc(sizeof(ushort) * (size_t)NN * EMB_DIM); // 51.2 MB
    int*    deg    = (int*)   alloc(sizeof(int)   * NN);        // deg+cursor adjacent:
    int*    cursor = (int*)   alloc(sizeof(int)   * NN);        // single memset below
    float*  dis    = (float*) alloc(sizeof(float) * NN);
    int*    rp     = (int*)   alloc(sizeof(int)   * (NN + 1));
    int2*   csr    = (int2*)  alloc(sizeof(int2)  * NUM_EDGES);             // 4.8 MB
    int*    bsum   = (int*)   alloc(sizeof(int)   * 1024);

    (void)hipMemsetAsync(deg, 0, sizeof(int) * NN * 2, stream);  // deg + cursor

    const int VB = (int)(((size_t)NN * EMB_DIM / 8) / 256);   // 12500
    k_conv <<<VB, 256, 0, stream>>>(emb, x0);
    k_count<<<CNT_NB, 256, 0, stream>>>(col, deg);
    k_scan1<<<SCAN_NB, SCAN_B, 0, stream>>>(deg, rp, bsum, dis);
    k_scan2<<<1, 1024, 0, stream>>>(bsum);
    k_scan3<<<SCAN_NB, SCAN_B, 0, stream>>>(rp, bsum);
    k_fill<<<CNT_NB, 256, 0, stream>>>(row, col, dis, rp, cursor, csr);

    const int GB = (int)(((size_t)NN * 8) / 256);             // 6250 (8 lanes/node)
    k_gath <<<GB, 256, 0, stream>>>(x0, rp, csr, x1);
    k_gath <<<GB, 256, 0, stream>>>(x1, rp, csr, x2);
    k_final<<<GB, 256, 0, stream>>>(x2, rp, csr, x0, x1, out);
}

// Round 10
// 235.780 us; speedup vs baseline: 1.0518x; 1.0518x over previous
//
#include <hip/hip_runtime.h>

#define NUM_USERS 100000
#define NUM_ITEMS 100000
#define EMB_DIM   128
#define NUM_EDGES 600000
#define NN        200000   // N_NODES

#define SCAN_B  256
#define SCAN_NB ((NN + SCAN_B - 1) / SCAN_B)   // 782
#define CNT_NB  ((NUM_EDGES + 255) / 256)

typedef __attribute__((ext_vector_type(8))) unsigned short ushort8_t;
typedef __attribute__((ext_vector_type(4))) float float4_t;

// bf16 helpers (RNE rounding)
__device__ inline float bf2f(unsigned short u) {
    unsigned int x = ((unsigned int)u) << 16;
    return __builtin_bit_cast(float, x);
}
__device__ inline unsigned short f2bf(float f) {
    unsigned int x = __builtin_bit_cast(unsigned int, f);
    x += 0x7fffu + ((x >> 16) & 1u);   // round-to-nearest-even
    return (unsigned short)(x >> 16);
}

// ---------- degree count (in-degree over col) ----------
__global__ void k_count(const int* __restrict__ col, int* __restrict__ deg) {
    int e = blockIdx.x * blockDim.x + threadIdx.x;
    if (e < NUM_EDGES) atomicAdd(&deg[col[e]], 1);
}

// ---------- scan part 1 + deg_inv_sqrt fused ----------
__global__ void k_scan1(const int* __restrict__ deg, int* __restrict__ rp,
                        int* __restrict__ bsum, float* __restrict__ dis) {
    __shared__ int s[SCAN_B];
    int tid = threadIdx.x;
    int i = blockIdx.x * SCAN_B + tid;
    int v = (i < NN) ? deg[i] : 0;
    s[tid] = v;
    __syncthreads();
    for (int off = 1; off < SCAN_B; off <<= 1) {
        int t = (tid >= off) ? s[tid - off] : 0;
        __syncthreads();
        s[tid] += t;
        __syncthreads();
    }
    if (i < NN) {
        rp[i]  = s[tid] - v;                    // exclusive within block
        dis[i] = (v > 0) ? 1.0f / sqrtf((float)v) : 0.0f;
    }
    if (tid == SCAN_B - 1) bsum[blockIdx.x] = s[tid];
}

__global__ void k_scan2(int* __restrict__ bsum) {
    __shared__ int s[1024];
    int tid = threadIdx.x;
    int v = (tid < SCAN_NB) ? bsum[tid] : 0;
    s[tid] = v;
    __syncthreads();
    for (int off = 1; off < 1024; off <<= 1) {
        int t = (tid >= off) ? s[tid - off] : 0;
        __syncthreads();
        s[tid] += t;
        __syncthreads();
    }
    if (tid < SCAN_NB) bsum[tid] = s[tid] - v;
}

__global__ void k_scan3(int* __restrict__ rp, const int* __restrict__ bsum) {
    int i = blockIdx.x * SCAN_B + threadIdx.x;
    if (i < NN) rp[i] += bsum[blockIdx.x];
    if (i == 0) rp[NN] = NUM_EDGES;
}

// ---------- CSR fill, packed (src, coef) ----------
__global__ void k_fill(const int* __restrict__ row, const int* __restrict__ col,
                       const float* __restrict__ dis, const int* __restrict__ rp,
                       int* __restrict__ cursor, int2* __restrict__ csr) {
    int e = blockIdx.x * blockDim.x + threadIdx.x;
    if (e >= NUM_EDGES) return;
    int r = row[e], c = col[e];
    int p = rp[c] + atomicAdd(&cursor[c], 1);
    csr[p] = make_int2(r, __builtin_bit_cast(int, dis[r] * dis[c]));
}

// ---------- layer 0 + conversion fused:
//   y1 = A * emb (f32 gather) -> x1 (bf16)
//   x0 = bf16(emb[own row])   (own-row lines are L2/L3-warm from the gather)
__global__ void k_gath0f(const float* __restrict__ emb, const int* __restrict__ rp,
                         const int2* __restrict__ csr,
                         ushort* __restrict__ x0, ushort* __restrict__ x1) {
    int t    = blockIdx.x * blockDim.x + threadIdx.x;
    int node = t >> 4;
    int lane = t & 15;
    if (node >= NN) return;
    int beg = rp[node], end = rp[node + 1];
    float a[8] = {0, 0, 0, 0, 0, 0, 0, 0};
    const int bd = lane * 8;
    for (int k = beg; k < end; k += 4) {
        const int last = end - 1;
        const int k1 = min(k + 1, last), k2 = min(k + 2, last), k3 = min(k + 3, last);
        const int2 e0 = csr[k], e1 = csr[k1], e2 = csr[k2], e3 = csr[k3];
        const float c0 = __builtin_bit_cast(float, e0.y);
        const float c1 = (k + 1 <= last) ? __builtin_bit_cast(float, e1.y) : 0.0f;
        const float c2 = (k + 2 <= last) ? __builtin_bit_cast(float, e2.y) : 0.0f;
        const float c3 = (k + 3 <= last) ? __builtin_bit_cast(float, e3.y) : 0.0f;
        const float4 u0 = *reinterpret_cast<const float4*>(emb + (size_t)e0.x * EMB_DIM + bd);
        const float4 u1 = *reinterpret_cast<const float4*>(emb + (size_t)e1.x * EMB_DIM + bd);
        const float4 u2 = *reinterpret_cast<const float4*>(emb + (size_t)e2.x * EMB_DIM + bd);
        const float4 u3 = *reinterpret_cast<const float4*>(emb + (size_t)e3.x * EMB_DIM + bd);
        const float4 w0 = *reinterpret_cast<const float4*>(emb + (size_t)e0.x * EMB_DIM + bd + 4);
        const float4 w1 = *reinterpret_cast<const float4*>(emb + (size_t)e1.x * EMB_DIM + bd + 4);
        const float4 w2 = *reinterpret_cast<const float4*>(emb + (size_t)e2.x * EMB_DIM + bd + 4);
        const float4 w3 = *reinterpret_cast<const float4*>(emb + (size_t)e3.x * EMB_DIM + bd + 4);
        a[0] += c0 * u0.x + c1 * u1.x + c2 * u2.x + c3 * u3.x;
        a[1] += c0 * u0.y + c1 * u1.y + c2 * u2.y + c3 * u3.y;
        a[2] += c0 * u0.z + c1 * u1.z + c2 * u2.z + c3 * u3.z;
        a[3] += c0 * u0.w + c1 * u1.w + c2 * u2.w + c3 * u3.w;
        a[4] += c0 * w0.x + c1 * w1.x + c2 * w2.x + c3 * w3.x;
        a[5] += c0 * w0.y + c1 * w1.y + c2 * w2.y + c3 * w3.y;
        a[6] += c0 * w0.z + c1 * w1.z + c2 * w2.z + c3 * w3.z;
        a[7] += c0 * w0.w + c1 * w1.w + c2 * w2.w + c3 * w3.w;
    }
    const size_t o = (size_t)node * EMB_DIM + bd;
    // own-row conversion: emb -> x0 (bf16)
    const float4 s0 = *reinterpret_cast<const float4*>(emb + o);
    const float4 s1 = *reinterpret_cast<const float4*>(emb + o + 4);
    ushort8_t xw;
    xw[0] = f2bf(s0.x); xw[1] = f2bf(s0.y); xw[2] = f2bf(s0.z); xw[3] = f2bf(s0.w);
    xw[4] = f2bf(s1.x); xw[5] = f2bf(s1.y); xw[6] = f2bf(s1.z); xw[7] = f2bf(s1.w);
    *reinterpret_cast<ushort8_t*>(x0 + o) = xw;
    // layer-1 output
    ushort8_t yw;
#pragma unroll
    for (int j = 0; j < 8; ++j) yw[j] = f2bf(a[j]);
    *reinterpret_cast<ushort8_t*>(x1 + o) = yw;
}

// ---------- propagation layer: y = A * x (bf16), store bf16 ----------
// 8 lanes/node, 32B/lane (2x ushort8); 4-wide edge unroll -> 8 independent
// 16B gathers in flight per thread. Plain stores: x1/x2 are re-read next.
__global__ void k_gath(const ushort* __restrict__ x, const int* __restrict__ rp,
                       const int2* __restrict__ csr, ushort* __restrict__ xn) {
    int t    = blockIdx.x * blockDim.x + threadIdx.x;
    int node = t >> 3;
    int lane = t & 7;
    if (node >= NN) return;
    int beg = rp[node], end = rp[node + 1];
    float a[16] = {0};
    const int bd = lane * 16;
    for (int k = beg; k < end; k += 4) {
        const int last = end - 1;
        const int k1 = min(k + 1, last), k2 = min(k + 2, last), k3 = min(k + 3, last);
        const int2 e0 = csr[k], e1 = csr[k1], e2 = csr[k2], e3 = csr[k3];
        const float c0 = __builtin_bit_cast(float, e0.y);
        const float c1 = (k + 1 <= last) ? __builtin_bit_cast(float, e1.y) : 0.0f;
        const float c2 = (k + 2 <= last) ? __builtin_bit_cast(float, e2.y) : 0.0f;
        const float c3 = (k + 3 <= last) ? __builtin_bit_cast(float, e3.y) : 0.0f;
        const ushort* p0 = x + (size_t)e0.x * EMB_DIM + bd;
        const ushort* p1 = x + (size_t)e1.x * EMB_DIM + bd;
        const ushort* p2 = x + (size_t)e2.x * EMB_DIM + bd;
        const ushort* p3 = x + (size_t)e3.x * EMB_DIM + bd;
        const ushort8_t v0a = *reinterpret_cast<const ushort8_t*>(p0);
        const ushort8_t v1a = *reinterpret_cast<const ushort8_t*>(p1);
        const ushort8_t v2a = *reinterpret_cast<const ushort8_t*>(p2);
        const ushort8_t v3a = *reinterpret_cast<const ushort8_t*>(p3);
        const ushort8_t v0b = *reinterpret_cast<const ushort8_t*>(p0 + 8);
        const ushort8_t v1b = *reinterpret_cast<const ushort8_t*>(p1 + 8);
        const ushort8_t v2b = *reinterpret_cast<const ushort8_t*>(p2 + 8);
        const ushort8_t v3b = *reinterpret_cast<const ushort8_t*>(p3 + 8);
#pragma unroll
        for (int j = 0; j < 8; ++j) {
            a[j]     += c0 * bf2f(v0a[j]) + c1 * bf2f(v1a[j]) +
                        c2 * bf2f(v2a[j]) + c3 * bf2f(v3a[j]);
            a[j + 8] += c0 * bf2f(v0b[j]) + c1 * bf2f(v1b[j]) +
                        c2 * bf2f(v2b[j]) + c3 * bf2f(v3b[j]);
        }
    }
    ushort8_t wa, wb;
#pragma unroll
    for (int j = 0; j < 8; ++j) { wa[j] = f2bf(a[j]); wb[j] = f2bf(a[j + 8]); }
    ushort* q = xn + (size_t)node * EMB_DIM + bd;
    *reinterpret_cast<ushort8_t*>(q)     = wa;
    *reinterpret_cast<ushort8_t*>(q + 8) = wb;
}

// ---------- final: y3 = A * x2;  out = (x0 + x1 + x2 + y3) * 0.25 ----------
// 16 lanes/node (R5/R8-proven: VGPR 32, occ ~68%, WRITE ~1.1x); NT out only.
__global__ void k_final(const ushort* __restrict__ x2, const int* __restrict__ rp,
                        const int2* __restrict__ csr,
                        const ushort* __restrict__ x0, const ushort* __restrict__ x1,
                        float* __restrict__ out) {
    int t    = blockIdx.x * blockDim.x + threadIdx.x;
    int node = t >> 4;
    int lane = t & 15;
    if (node >= NN) return;
    int beg = rp[node], end = rp[node + 1];
    float a[8] = {0, 0, 0, 0, 0, 0, 0, 0};
    const int bd = lane * 8;
    for (int k = beg; k < end; k += 4) {
        const int last = end - 1;
        const int k1 = min(k + 1, last), k2 = min(k + 2, last), k3 = min(k + 3, last);
        const int2 e0 = csr[k], e1 = csr[k1], e2 = csr[k2], e3 = csr[k3];
        const float c0 = __builtin_bit_cast(float, e0.y);
        const float c1 = (k + 1 <= last) ? __builtin_bit_cast(float, e1.y) : 0.0f;
        const float c2 = (k + 2 <= last) ? __builtin_bit_cast(float, e2.y) : 0.0f;
        const float c3 = (k + 3 <= last) ? __builtin_bit_cast(float, e3.y) : 0.0f;
        const ushort8_t v0 = *reinterpret_cast<const ushort8_t*>(x2 + (size_t)e0.x * EMB_DIM + bd);
        const ushort8_t v1 = *reinterpret_cast<const ushort8_t*>(x2 + (size_t)e1.x * EMB_DIM + bd);
        const ushort8_t v2 = *reinterpret_cast<const ushort8_t*>(x2 + (size_t)e2.x * EMB_DIM + bd);
        const ushort8_t v3 = *reinterpret_cast<const ushort8_t*>(x2 + (size_t)e3.x * EMB_DIM + bd);
#pragma unroll
        for (int j = 0; j < 8; ++j)
            a[j] += c0 * bf2f(v0[j]) + c1 * bf2f(v1[j]) +
                    c2 * bf2f(v2[j]) + c3 * bf2f(v3[j]);
    }
    const size_t o = (size_t)node * EMB_DIM + bd;
    const ushort8_t w0 = *reinterpret_cast<const ushort8_t*>(x0 + o);
    const ushort8_t w1 = *reinterpret_cast<const ushort8_t*>(x1 + o);
    const ushort8_t w2 = *reinterpret_cast<const ushort8_t*>(x2 + o);
    float4_t r0, r1;
#pragma unroll
    for (int j = 0; j < 4; ++j)
        r0[j] = (bf2f(w0[j]) + bf2f(w1[j]) + bf2f(w2[j]) + a[j]) * 0.25f;
#pragma unroll
    for (int j = 0; j < 4; ++j)
        r1[j] = (bf2f(w0[j + 4]) + bf2f(w1[j + 4]) + bf2f(w2[j + 4]) + a[j + 4]) * 0.25f;
    // out is never re-read: nontemporal keeps x0/x1/x2 L3-resident for the gather
    __builtin_nontemporal_store(r0, reinterpret_cast<float4_t*>(out + o));
    __builtin_nontemporal_store(r1, reinterpret_cast<float4_t*>(out + o) + 1);
}

extern "C" void kernel_launch(void* const* d_in, const int* in_sizes, int n_in,
                              void* d_out, int out_size, void* d_ws, size_t ws_size,
                              hipStream_t stream) {
    const int*   edges = (const int*)d_in[0];
    const int*   row   = edges;               // edge_index[0]
    const int*   col   = edges + NUM_EDGES;   // edge_index[1]
    const float* emb   = (const float*)d_in[1];
    float*       out   = (float*)d_out;

    char*  ws  = (char*)d_ws;
    size_t off = 0;
    auto alloc = [&](size_t bytes) {
        void* p = ws + off;
        off += (bytes + 255) & ~(size_t)255;
        return p;
    };
    ushort* x0     = (ushort*)alloc(sizeof(ushort) * (size_t)NN * EMB_DIM); // 51.2 MB
    ushort* x1     = (ushort*)alloc(sizeof(ushort) * (size_t)NN * EMB_DIM); // 51.2 MB
    ushort* x2     = (ushort*)alloc(sizeof(ushort) * (size_t)NN * EMB_DIM); // 51.2 MB
    int*    deg    = (int*)   alloc(sizeof(int)   * NN);        // deg+cursor adjacent:
    int*    cursor = (int*)   alloc(sizeof(int)   * NN);        // single memset below
    float*  dis    = (float*) alloc(sizeof(float) * NN);
    int*    rp     = (int*)   alloc(sizeof(int)   * (NN + 1));
    int2*   csr    = (int2*)  alloc(sizeof(int2)  * NUM_EDGES);             // 4.8 MB
    int*    bsum   = (int*)   alloc(sizeof(int)   * 1024);

    (void)hipMemsetAsync(deg, 0, sizeof(int) * NN * 2, stream);  // deg + cursor

    k_count<<<CNT_NB, 256, 0, stream>>>(col, deg);
    k_scan1<<<SCAN_NB, SCAN_B, 0, stream>>>(deg, rp, bsum, dis);
    k_scan2<<<1, 1024, 0, stream>>>(bsum);
    k_scan3<<<SCAN_NB, SCAN_B, 0, stream>>>(rp, bsum);
    k_fill<<<CNT_NB, 256, 0, stream>>>(row, col, dis, rp, cursor, csr);

    const int FB = (int)(((size_t)NN * 16) / 256);            // 12500 (16 lanes/node)
    const int GB = (int)(((size_t)NN * 8)  / 256);            // 6250  (8 lanes/node)
    k_gath0f<<<FB, 256, 0, stream>>>(emb, rp, csr, x0, x1);
    k_gath  <<<GB, 256, 0, stream>>>(x1, rp, csr, x2);
    k_final <<<FB, 256, 0, stream>>>(x2, rp, csr, x0, x1, out);
}

// Round 11
// 224.528 us; speedup vs baseline: 1.1046x; 1.0501x over previous
//
#include <hip/hip_runtime.h>

#define NUM_USERS 100000
#define NUM_ITEMS 100000
#define EMB_DIM   128
#define NUM_EDGES 600000
#define NN        200000   // N_NODES

#define SCAN_B  256
#define SCAN_NB ((NN + SCAN_B - 1) / SCAN_B)   // 782
#define CNT_NB  ((NUM_EDGES + 255) / 256)

typedef __attribute__((ext_vector_type(8))) unsigned short ushort8_t;
typedef __attribute__((ext_vector_type(4))) float float4_t;

// bf16 helpers (RNE rounding)
__device__ inline float bf2f(unsigned short u) {
    unsigned int x = ((unsigned int)u) << 16;
    return __builtin_bit_cast(float, x);
}
__device__ inline unsigned short f2bf(float f) {
    unsigned int x = __builtin_bit_cast(unsigned int, f);
    x += 0x7fffu + ((x >> 16) & 1u);   // round-to-nearest-even
    return (unsigned short)(x >> 16);
}

// ---------- emb f32 -> x0 bf16: canonical grid-stride stream kernel ----------
// 2048 blocks x 256 thr; per iter: 32B load (2x float4) + 16B store. No NT.
#define CONV_ITERS ((size_t)NN * EMB_DIM / 8)   // 3.2M
__global__ void k_conv(const float* __restrict__ emb, ushort* __restrict__ x0) {
    const size_t stride = (size_t)gridDim.x * blockDim.x;
    for (size_t i = blockIdx.x * (size_t)blockDim.x + threadIdx.x;
         i < CONV_ITERS; i += stride) {
        const float4_t v0 = reinterpret_cast<const float4_t*>(emb)[2 * i];
        const float4_t v1 = reinterpret_cast<const float4_t*>(emb)[2 * i + 1];
        ushort8_t w;
#pragma unroll
        for (int j = 0; j < 4; ++j) { w[j] = f2bf(v0[j]); w[j + 4] = f2bf(v1[j]); }
        reinterpret_cast<ushort8_t*>(x0)[i] = w;
    }
}

// ---------- degree count (in-degree over col) ----------
__global__ void k_count(const int* __restrict__ col, int* __restrict__ deg) {
    int e = blockIdx.x * blockDim.x + threadIdx.x;
    if (e < NUM_EDGES) atomicAdd(&deg[col[e]], 1);
}

// ---------- scan part 1 + deg_inv_sqrt fused ----------
__global__ void k_scan1(const int* __restrict__ deg, int* __restrict__ rp,
                        int* __restrict__ bsum, float* __restrict__ dis) {
    __shared__ int s[SCAN_B];
    int tid = threadIdx.x;
    int i = blockIdx.x * SCAN_B + tid;
    int v = (i < NN) ? deg[i] : 0;
    s[tid] = v;
    __syncthreads();
    for (int off = 1; off < SCAN_B; off <<= 1) {
        int t = (tid >= off) ? s[tid - off] : 0;
        __syncthreads();
        s[tid] += t;
        __syncthreads();
    }
    if (i < NN) {
        rp[i]  = s[tid] - v;                    // exclusive within block
        dis[i] = (v > 0) ? 1.0f / sqrtf((float)v) : 0.0f;
    }
    if (tid == SCAN_B - 1) bsum[blockIdx.x] = s[tid];
}

__global__ void k_scan2(int* __restrict__ bsum) {
    __shared__ int s[1024];
    int tid = threadIdx.x;
    int v = (tid < SCAN_NB) ? bsum[tid] : 0;
    s[tid] = v;
    __syncthreads();
    for (int off = 1; off < 1024; off <<= 1) {
        int t = (tid >= off) ? s[tid - off] : 0;
        __syncthreads();
        s[tid] += t;
        __syncthreads();
    }
    if (tid < SCAN_NB) bsum[tid] = s[tid] - v;
}

__global__ void k_scan3(int* __restrict__ rp, const int* __restrict__ bsum) {
    int i = blockIdx.x * SCAN_B + threadIdx.x;
    if (i < NN) rp[i] += bsum[blockIdx.x];
    if (i == 0) rp[NN] = NUM_EDGES;
}

// ---------- CSR fill, packed (src, coef) ----------
__global__ void k_fill(const int* __restrict__ row, const int* __restrict__ col,
                       const float* __restrict__ dis, const int* __restrict__ rp,
                       int* __restrict__ cursor, int2* __restrict__ csr) {
    int e = blockIdx.x * blockDim.x + threadIdx.x;
    if (e >= NUM_EDGES) return;
    int r = row[e], c = col[e];
    int p = rp[c] + atomicAdd(&cursor[c], 1);
    csr[p] = make_int2(r, __builtin_bit_cast(int, dis[r] * dis[c]));
}

// ---------- propagation layer: y = A * x (bf16), store bf16 ----------
// 8 lanes/node, 32B/lane (2x ushort8); 4-wide edge unroll -> 8 independent
// 16B gathers in flight per thread. Plain stores: x1/x2 are re-read next.
__global__ void k_gath(const ushort* __restrict__ x, const int* __restrict__ rp,
                       const int2* __restrict__ csr, ushort* __restrict__ xn) {
    int t    = blockIdx.x * blockDim.x + threadIdx.x;
    int node = t >> 3;
    int lane = t & 7;
    if (node >= NN) return;
    int beg = rp[node], end = rp[node + 1];
    float a[16] = {0};
    const int bd = lane * 16;
    for (int k = beg; k < end; k += 4) {
        const int last = end - 1;
        const int k1 = min(k + 1, last), k2 = min(k + 2, last), k3 = min(k + 3, last);
        const int2 e0 = csr[k], e1 = csr[k1], e2 = csr[k2], e3 = csr[k3];
        const float c0 = __builtin_bit_cast(float, e0.y);
        const float c1 = (k + 1 <= last) ? __builtin_bit_cast(float, e1.y) : 0.0f;
        const float c2 = (k + 2 <= last) ? __builtin_bit_cast(float, e2.y) : 0.0f;
        const float c3 = (k + 3 <= last) ? __builtin_bit_cast(float, e3.y) : 0.0f;
        const ushort* p0 = x + (size_t)e0.x * EMB_DIM + bd;
        const ushort* p1 = x + (size_t)e1.x * EMB_DIM + bd;
        const ushort* p2 = x + (size_t)e2.x * EMB_DIM + bd;
        const ushort* p3 = x + (size_t)e3.x * EMB_DIM + bd;
        const ushort8_t v0a = *reinterpret_cast<const ushort8_t*>(p0);
        const ushort8_t v1a = *reinterpret_cast<const ushort8_t*>(p1);
        const ushort8_t v2a = *reinterpret_cast<const ushort8_t*>(p2);
        const ushort8_t v3a = *reinterpret_cast<const ushort8_t*>(p3);
        const ushort8_t v0b = *reinterpret_cast<const ushort8_t*>(p0 + 8);
        const ushort8_t v1b = *reinterpret_cast<const ushort8_t*>(p1 + 8);
        const ushort8_t v2b = *reinterpret_cast<const ushort8_t*>(p2 + 8);
        const ushort8_t v3b = *reinterpret_cast<const ushort8_t*>(p3 + 8);
#pragma unroll
        for (int j = 0; j < 8; ++j) {
            a[j]     += c0 * bf2f(v0a[j]) + c1 * bf2f(v1a[j]) +
                        c2 * bf2f(v2a[j]) + c3 * bf2f(v3a[j]);
            a[j + 8] += c0 * bf2f(v0b[j]) + c1 * bf2f(v1b[j]) +
                        c2 * bf2f(v2b[j]) + c3 * bf2f(v3b[j]);
        }
    }
    ushort8_t wa, wb;
#pragma unroll
    for (int j = 0; j < 8; ++j) { wa[j] = f2bf(a[j]); wb[j] = f2bf(a[j + 8]); }
    ushort* q = xn + (size_t)node * EMB_DIM + bd;
    *reinterpret_cast<ushort8_t*>(q)     = wa;
    *reinterpret_cast<ushort8_t*>(q + 8) = wb;
}

// ---------- final: y3 = A * x2;  out = (x0 + x1 + x2 + y3) * 0.25 ----------
// 16 lanes/node (proven: VGPR 32, occ ~68%); NT store for out only.
__global__ void k_final(const ushort* __restrict__ x2, const int* __restrict__ rp,
                        const int2* __restrict__ csr,
                        const ushort* __restrict__ x0, const ushort* __restrict__ x1,
                        float* __restrict__ out) {
    int t    = blockIdx.x * blockDim.x + threadIdx.x;
    int node = t >> 4;
    int lane = t & 15;
    if (node >= NN) return;
    int beg = rp[node], end = rp[node + 1];
    float a[8] = {0, 0, 0, 0, 0, 0, 0, 0};
    const int bd = lane * 8;
    for (int k = beg; k < end; k += 4) {
        const int last = end - 1;
        const int k1 = min(k + 1, last), k2 = min(k + 2, last), k3 = min(k + 3, last);
        const int2 e0 = csr[k], e1 = csr[k1], e2 = csr[k2], e3 = csr[k3];
        const float c0 = __builtin_bit_cast(float, e0.y);
        const float c1 = (k + 1 <= last) ? __builtin_bit_cast(float, e1.y) : 0.0f;
        const float c2 = (k + 2 <= last) ? __builtin_bit_cast(float, e2.y) : 0.0f;
        const float c3 = (k + 3 <= last) ? __builtin_bit_cast(float, e3.y) : 0.0f;
        const ushort8_t v0 = *reinterpret_cast<const ushort8_t*>(x2 + (size_t)e0.x * EMB_DIM + bd);
        const ushort8_t v1 = *reinterpret_cast<const ushort8_t*>(x2 + (size_t)e1.x * EMB_DIM + bd);
        const ushort8_t v2 = *reinterpret_cast<const ushort8_t*>(x2 + (size_t)e2.x * EMB_DIM + bd);
        const ushort8_t v3 = *reinterpret_cast<const ushort8_t*>(x2 + (size_t)e3.x * EMB_DIM + bd);
#pragma unroll
        for (int j = 0; j < 8; ++j)
            a[j] += c0 * bf2f(v0[j]) + c1 * bf2f(v1[j]) +
                    c2 * bf2f(v2[j]) + c3 * bf2f(v3[j]);
    }
    const size_t o = (size_t)node * EMB_DIM + bd;
    const ushort8_t w0 = *reinterpret_cast<const ushort8_t*>(x0 + o);
    const ushort8_t w1 = *reinterpret_cast<const ushort8_t*>(x1 + o);
    const ushort8_t w2 = *reinterpret_cast<const ushort8_t*>(x2 + o);
    float4_t r0, r1;
#pragma unroll
    for (int j = 0; j < 4; ++j)
        r0[j] = (bf2f(w0[j]) + bf2f(w1[j]) + bf2f(w2[j]) + a[j]) * 0.25f;
#pragma unroll
    for (int j = 0; j < 4; ++j)
        r1[j] = (bf2f(w0[j + 4]) + bf2f(w1[j + 4]) + bf2f(w2[j + 4]) + a[j + 4]) * 0.25f;
    // out is never re-read: nontemporal keeps x0/x1/x2 L3-resident for the gather
    __builtin_nontemporal_store(r0, reinterpret_cast<float4_t*>(out + o));
    __builtin_nontemporal_store(r1, reinterpret_cast<float4_t*>(out + o) + 1);
}

extern "C" void kernel_launch(void* const* d_in, const int* in_sizes, int n_in,
                              void* d_out, int out_size, void* d_ws, size_t ws_size,
                              hipStream_t stream) {
    const int*   edges = (const int*)d_in[0];
    const int*   row   = edges;               // edge_index[0]
    const int*   col   = edges + NUM_EDGES;   // edge_index[1]
    const float* emb   = (const float*)d_in[1];
    float*       out   = (float*)d_out;

    char*  ws  = (char*)d_ws;
    size_t off = 0;
    auto alloc = [&](size_t bytes) {
        void* p = ws + off;
        off += (bytes + 255) & ~(size_t)255;
        return p;
    };
    ushort* x0     = (ushort*)alloc(sizeof(ushort) * (size_t)NN * EMB_DIM); // 51.2 MB
    ushort* x1     = (ushort*)alloc(sizeof(ushort) * (size_t)NN * EMB_DIM); // 51.2 MB
    ushort* x2     = (ushort*)alloc(sizeof(ushort) * (size_t)NN * EMB_DIM); // 51.2 MB
    int*    deg    = (int*)   alloc(sizeof(int)   * NN);        // deg+cursor adjacent:
    int*    cursor = (int*)   alloc(sizeof(int)   * NN);        // single memset below
    float*  dis    = (float*) alloc(sizeof(float) * NN);
    int*    rp     = (int*)   alloc(sizeof(int)   * (NN + 1));
    int2*   csr    = (int2*)  alloc(sizeof(int2)  * NUM_EDGES);             // 4.8 MB
    int*    bsum   = (int*)   alloc(sizeof(int)   * 1024);

    (void)hipMemsetAsync(deg, 0, sizeof(int) * NN * 2, stream);  // deg + cursor

    k_conv <<<2048, 256, 0, stream>>>(emb, x0);     // grid-stride stream kernel
    k_count<<<CNT_NB, 256, 0, stream>>>(col, deg);
    k_scan1<<<SCAN_NB, SCAN_B, 0, stream>>>(deg, rp, bsum, dis);
    k_scan2<<<1, 1024, 0, stream>>>(bsum);
    k_scan3<<<SCAN_NB, SCAN_B, 0, stream>>>(rp, bsum);
    k_fill <<<CNT_NB, 256, 0, stream>>>(row, col, dis, rp, cursor, csr);

    const int GB = (int)(((size_t)NN * 8)  / 256);            // 6250  (8 lanes/node)
    const int FB = (int)(((size_t)NN * 16) / 256);            // 12500 (16 lanes/node)
    k_gath <<<GB, 256, 0, stream>>>(x0, rp, csr, x1);
    k_gath <<<GB, 256, 0, stream>>>(x1, rp, csr, x2);
    k_final<<<FB, 256, 0, stream>>>(x2, rp, csr, x0, x1, out);
}